// Round 1
// baseline (216.458 us; speedup 1.0000x reference)
//
#include <hip/hip_runtime.h>

typedef short bf16x8 __attribute__((ext_vector_type(8)));
typedef float f32x4 __attribute__((ext_vector_type(4)));
typedef unsigned short ushort8 __attribute__((ext_vector_type(8)));
typedef unsigned short ushort4v __attribute__((ext_vector_type(4)));

#define BATCH 16
#define DCAT 512
#define CIN 256
#define COUT 256
#define HH 64
#define WW 64
#define HP 66
#define WP 66
#define PLANE (HP * WP * 8)  // shorts per c8-plane

__device__ __forceinline__ unsigned short f2bf(float f) {
  unsigned int u = __float_as_uint(f);
  unsigned int r = (u + 0x7fffu + ((u >> 16) & 1u)) >> 16;
  return (unsigned short)r;
}

// ---------------- MLP layer: one wave per output element (b,c).
template <int IN_DIM>
__global__ void __launch_bounds__(256) mlp_layer(const float* __restrict__ in,
                                                 const float* __restrict__ w,
                                                 const float* __restrict__ bias,
                                                 float* __restrict__ out) {
  int wid = threadIdx.x >> 6, lane = threadIdx.x & 63;
  int oidx = blockIdx.x * 4 + wid;  // (b<<8)|c
  int b = oidx >> 8, c = oidx & 255;
  const float* wr = w + (size_t)c * IN_DIM;
  const float* ir = in + (size_t)b * IN_DIM;
  float sum = 0.f;
#pragma unroll
  for (int d0 = 0; d0 < IN_DIM; d0 += 256) {
    f32x4 wv = *(const f32x4*)(wr + d0 + lane * 4);
    f32x4 iv = *(const f32x4*)(ir + d0 + lane * 4);
    sum += wv[0] * iv[0] + wv[1] * iv[1] + wv[2] * iv[2] + wv[3] * iv[3];
  }
#pragma unroll
  for (int off = 32; off; off >>= 1) sum += __shfl_xor(sum, off, 64);
  if (lane == 0) {
    float a = sum + bias[c];
    out[oidx] = a >= 0.f ? a : 0.01f * a;
  }
}

// ---------------- consolidated prep:
// blocks [0,1024): fused MLP-layer-3 + padded/scaled/c8-blocked bf16 x
//   block = (b, c8, half); each thread: 2 pixel-groups = 16 x-loads in flight.
// blocks [1024,1600): conv_w (O,I,3,3) fp32 -> fragment-major bf16 wt:
//   element (t,o,i): f = ((t*16 + o/16)*8 + (i/8)/4)*4 + (i/8)%4
//   off_shorts = (f*16 + o%16)*8 + i%8
//   -> one wave B-frag load (o in 16s, i-chunk in 4s) = 1 KiB contiguous.
__global__ void __launch_bounds__(256) prep_all(const float* __restrict__ t1,
                                                const float* __restrict__ w2,
                                                const float* __restrict__ b2,
                                                const float* __restrict__ x,
                                                const float* __restrict__ cw,
                                                unsigned short* __restrict__ xpad,
                                                unsigned short* __restrict__ wt) {
  int blk = blockIdx.x;
  int tid = threadIdx.x;

  if (blk >= 1024) {  // ---- prep_w part
    int idx = (blk - 1024) * 256 + tid;  // 9*256*64 = 147456 threads
    int t = idx / 16384;
    int r = idx - t * 16384;  // o*64 + i4
    int o = r >> 6, i4 = r & 63;
    ushort4v v;
#pragma unroll
    for (int j = 0; j < 4; j++) v[j] = f2bf(cw[(o * 256 + i4 * 4 + j) * 9 + t]);
    int ob = o >> 4, oo = o & 15;
    int g4 = i4 >> 3, gr = (i4 >> 1) & 3, j0 = (i4 & 1) * 4;
    size_t off = ((size_t)((((t * 16 + ob) * 8 + g4) * 4 + gr) * 16 + oo)) * 8 + j0;
    *(ushort4v*)(wt + off) = v;
    return;
  }

  // ---- prep_x part: blk = (b<<6) | (c8<<1) | h
  int h = blk & 1, c8 = (blk >> 1) & 31, b = blk >> 6;
  int wid = tid >> 6, lane = tid & 63;

  // MLP loads first (longest dependency chain: load -> shuffle tree -> 2 barriers)
  float tv = t1[b * CIN + tid];
  float pj[8];
#pragma unroll
  for (int j = 0; j < 8; j++) pj[j] = w2[(size_t)(c8 * 8 + j) * CIN + tid] * tv;

  // 16 independent x loads (2 pixel-groups x 8 channel-planes)
  const float* xb = x + ((size_t)(b * CIN + c8 * 8)) * (HH * WW);
  int gg0 = h * 512 + tid;  // pixel-group: hh=(gg>>4)+1, w0=(gg&15)*4+1
  int gg1 = gg0 + 256;
  int hh0 = (gg0 >> 4) + 1, w00 = (gg0 & 15) * 4 + 1;
  int hh1 = (gg1 >> 4) + 1, w01 = (gg1 & 15) * 4 + 1;
  int base0 = (hh0 - 1) * WW + (w00 - 1);
  int base1 = (hh1 - 1) * WW + (w01 - 1);
  f32x4 v0[8], v1[8];
#pragma unroll
  for (int j = 0; j < 8; j++) v0[j] = *(const f32x4*)(xb + j * (HH * WW) + base0);
#pragma unroll
  for (int j = 0; j < 8; j++) v1[j] = *(const f32x4*)(xb + j * (HH * WW) + base1);

  // butterfly-reduce the 8 style dots
#pragma unroll
  for (int off = 32; off; off >>= 1)
#pragma unroll
    for (int j = 0; j < 8; j++) pj[j] += __shfl_xor(pj[j], off, 64);
  __shared__ float red[4][8];
  __shared__ float sv_sh[8];
  if (lane == 0)
#pragma unroll
    for (int j = 0; j < 8; j++) red[wid][j] = pj[j];
  __syncthreads();
  if (tid < 8) {
    float a = red[0][tid] + red[1][tid] + red[2][tid] + red[3][tid] + b2[c8 * 8 + tid];
    sv_sh[tid] = a >= 0.f ? a : 0.01f * a;
  }
  __syncthreads();
  float sv[8];
#pragma unroll
  for (int j = 0; j < 8; j++) sv[j] = sv_sh[j];

  unsigned short* xp = xpad + ((size_t)(b * 32 + c8)) * PLANE;

  // zero border: half h covers 130 of the 260 border cells
  if (tid < 130) {
    int i = h * 130 + tid;
    int bh, bw;
    if (i < 66) { bh = 0; bw = i; }
    else if (i < 132) { bh = 65; bw = i - 66; }
    else if (i < 196) { bh = i - 132 + 1; bw = 0; }
    else { bh = i - 196 + 1; bw = 65; }
    ushort8 z = {0, 0, 0, 0, 0, 0, 0, 0};
    *(ushort8*)(xp + (bh * WP + bw) * 8) = z;
  }

  // convert + store (2 groups x 4 px x 8 ch = 2 x 64B contiguous per thread)
  unsigned short* op0 = xp + (hh0 * WP + w00) * 8;
  unsigned short* op1 = xp + (hh1 * WP + w01) * 8;
#pragma unroll
  for (int t2 = 0; t2 < 4; t2++) {
    ushort8 o;
#pragma unroll
    for (int j = 0; j < 8; j++) o[j] = f2bf(v0[j][t2] * sv[j]);
    *(ushort8*)(op0 + t2 * 8) = o;
  }
#pragma unroll
  for (int t2 = 0; t2 < 4; t2++) {
    ushort8 o;
#pragma unroll
    for (int j = 0; j < 8; j++) o[j] = f2bf(v1[j][t2] * sv[j]);
    *(ushort8*)(op1 + t2 * 8) = o;
  }
}

// ---------------- implicit-GEMM conv: BM=128 px, BN=256 out, BK=64
// 2-phase pipeline: A double-buffered in LDS (stage s+1 overlaps MFMA of s,
// one barrier per K-step); B read direct from global (1.125 MiB, L2-resident)
// as coalesced 1 KiB/wave fragment loads from fragment-major wt.
__device__ __forceinline__ void gl2lds16(const void* g, void* l) {
  __builtin_amdgcn_global_load_lds((const __attribute__((address_space(1))) void*)g,
                                   (__attribute__((address_space(3))) void*)l, 16, 0, 0);
}

__global__ void __launch_bounds__(512, 4) gemm_conv(const unsigned short* __restrict__ xpad,
                                                    const unsigned short* __restrict__ wt,
                                                    float* __restrict__ out) {
  __shared__ unsigned short As[2 * 128 * 64];  // [buf][pixel][64ch], XOR-swizzled chunks
  int tid = threadIdx.x;
  int wid = tid >> 6, lane = tid & 63;
  int bid = blockIdx.x;
  // XCD swizzle: XCD x covers m_t in [x*64, x*64+64) = 2 contiguous images.
  int m_t = (bid & 7) * 64 + (bid >> 3);
  int m0 = m_t << 7;
  int b = m0 >> 12;
  int h0 = (m0 >> 6) & 63;           // tile covers image rows h0, h0+1
  int wm = wid & 1, wn = wid >> 1;   // 2x4 wave grid, each wave 64x64

  f32x4 acc[4][4];
#pragma unroll
  for (int mi = 0; mi < 4; mi++)
#pragma unroll
    for (int ni = 0; ni < 4; ni++) acc[mi][ni] = (f32x4){0.f, 0.f, 0.f, 0.f};

  // ---- A stager lane invariants (global lane id = tid)
  int p = tid >> 3;                  // pixel 0..63 (second load: +WP row -> 64..127)
  int cs = tid & 7;                  // chunk slot in LDS row
  int gsA = cs ^ (p & 7);            // XOR swizzle: LDS slot cs holds global chunk gsA
  const unsigned short* aStage =
      xpad + ((size_t)((b * 32 + gsA) * HP + h0)) * (WP * 8) + p * 8;  // step 0

  // ---- B direct-load pointer (fragment-major wt), per lane
  int qa = lane >> 4;
  const char* bp = (const char*)wt + wn * 32768 + qa * 256 + (lane & 15) * 16;

  // ---- A reader frag offsets (bytes into As), XOR-unswizzled
  int rA = wm * 64 + (lane & 15);
  int offA0 = rA * 128 + ((qa ^ (rA & 7)) * 16);
  int offA1 = rA * 128 + (((qa + 4) ^ (rA & 7)) * 16);

  char* AsB = (char*)As;
  int stDst = wid * 1024;  // this wave's stage half-0 byte offset within a buffer

  // prologue: stage step 0 into buffer 0
  gl2lds16(aStage, AsB + stDst);
  gl2lds16(aStage + WP * 8, AsB + 8192 + stDst);
  aStage += 8 * PLANE;  // -> step 1 (kc2: 0->1)
  __syncthreads();

  int bufoff = 0;
  for (int s = 0; s < 36; s++) {  // step s: tap = s>>2, kc2 = s&3
    // B fragment loads for step s (issued FIRST so vmcnt waits before the
    // MFMA clusters do not force the stage loads to complete)
    bf16x8 bv0[4], bv1[4];
#pragma unroll
    for (int ni = 0; ni < 4; ni++) {
      bv0[ni] = *(const bf16x8*)(bp + ni * 8192);
      bv1[ni] = *(const bf16x8*)(bp + ni * 8192 + 1024);
    }

    // stage step s+1 into the other buffer (stays in flight across the MFMAs;
    // the barrier's implicit vmcnt(0) drain lands after ~32 MFMAs of cover)
    if (s < 35) {
      char* d = AsB + (bufoff ^ 16384) + stDst;
      gl2lds16(aStage, d);
      gl2lds16(aStage + WP * 8, d + 8192);
      int sn = s + 1;  // step just staged; advance pointer to step sn+1
      if ((sn & 3) != 3) {
        aStage += 8 * PLANE;            // kc2++
      } else {
        int tapn = sn >> 2;             // completed tap
        aStage -= 24 * PLANE;           // kc2 3->0
        aStage += (tapn % 3 != 2) ? 8 : (WP - 2) * 8;  // kw++ / kh++,kw=0
      }
    }

    // compute step s from As[bufoff]
#pragma unroll
    for (int kb = 0; kb < 2; kb++) {
      int oa = (kb ? offA1 : offA0) + bufoff;
      bf16x8 av[4];
#pragma unroll
      for (int mi = 0; mi < 4; mi++)
        av[mi] = *(const bf16x8*)(AsB + oa + mi * 2048);
#pragma unroll
      for (int mi = 0; mi < 4; mi++)
#pragma unroll
        for (int ni = 0; ni < 4; ni++)
          acc[mi][ni] = __builtin_amdgcn_mfma_f32_16x16x32_bf16(
              av[mi], kb ? bv1[ni] : bv0[ni], acc[mi][ni], 0, 0, 0);
    }

    __syncthreads();
    bufoff ^= 16384;
    bp += ((s & 3) != 3) ? 2048 : 124928;  // kc2++ / tap++,kc2=0
  }

  // ---- epilogue: D row = pixel (quad*4+reg), col = o (lane&15)
  int pixbase = m0 & 4095;
  int quad = lane >> 4;
  int col = lane & 15;
#pragma unroll
  for (int mi = 0; mi < 4; mi++) {
    int pm = pixbase + wm * 64 + mi * 16 + quad * 4;
#pragma unroll
    for (int ni = 0; ni < 4; ni++) {
      int on = wn * 64 + ni * 16 + col;
      float* op = out + ((size_t)(b * COUT + on) << 12) + pm;
      *(f32x4*)op = acc[mi][ni];
    }
  }
}

extern "C" void kernel_launch(void* const* d_in, const int* in_sizes, int n_in,
                              void* d_out, int out_size, void* d_ws, size_t ws_size,
                              hipStream_t stream) {
  const float* x = (const float*)d_in[0];
  const float* y = (const float*)d_in[1];
  const float* w0 = (const float*)d_in[2];
  const float* b0 = (const float*)d_in[3];
  const float* w1 = (const float*)d_in[4];
  const float* b1 = (const float*)d_in[5];
  const float* w2 = (const float*)d_in[6];
  const float* b2 = (const float*)d_in[7];
  const float* cw = (const float*)d_in[8];
  float* out = (float*)d_out;

  char* ws = (char*)d_ws;
  float* t0 = (float*)ws;                              // 16 KiB
  float* t1 = (float*)(ws + 16384);                    // 16 KiB
  unsigned short* wt = (unsigned short*)(ws + 32768);  // 1.125 MiB
  unsigned short* xpad = (unsigned short*)(ws + 32768 + 9 * COUT * CIN * 2);

  mlp_layer<DCAT><<<BATCH * CIN / 4, 256, 0, stream>>>(y, w0, b0, t0);
  mlp_layer<CIN><<<BATCH * CIN / 4, 256, 0, stream>>>(t0, w1, b1, t1);
  prep_all<<<1024 + 576, 256, 0, stream>>>(t1, w2, b2, x, cw, xpad, wt);
  gemm_conv<<<BATCH * HH * WW / 128, 512, 0, stream>>>(xpad, wt, out);
}

// Round 3
// 209.303 us; speedup vs baseline: 1.0342x; 1.0342x over previous
//
#include <hip/hip_runtime.h>

typedef short bf16x8 __attribute__((ext_vector_type(8)));
typedef float f32x4 __attribute__((ext_vector_type(4)));
typedef unsigned short ushort8 __attribute__((ext_vector_type(8)));
typedef unsigned short ushort4v __attribute__((ext_vector_type(4)));

#define BATCH 16
#define DCAT 512
#define CIN 256
#define COUT 256
#define HH 64
#define WW 64
#define HP 66
#define WP 66
#define PLANE (HP * WP * 8)  // shorts per c8-plane

__device__ __forceinline__ unsigned short f2bf(float f) {
  unsigned int u = __float_as_uint(f);
  unsigned int r = (u + 0x7fffu + ((u >> 16) & 1u)) >> 16;
  return (unsigned short)r;
}

// ---------------- MLP layer: one wave per output element (b,c).
template <int IN_DIM>
__global__ void __launch_bounds__(256) mlp_layer(const float* __restrict__ in,
                                                 const float* __restrict__ w,
                                                 const float* __restrict__ bias,
                                                 float* __restrict__ out) {
  int wid = threadIdx.x >> 6, lane = threadIdx.x & 63;
  int oidx = blockIdx.x * 4 + wid;  // (b<<8)|c
  int b = oidx >> 8, c = oidx & 255;
  const float* wr = w + (size_t)c * IN_DIM;
  const float* ir = in + (size_t)b * IN_DIM;
  float sum = 0.f;
#pragma unroll
  for (int d0 = 0; d0 < IN_DIM; d0 += 256) {
    f32x4 wv = *(const f32x4*)(wr + d0 + lane * 4);
    f32x4 iv = *(const f32x4*)(ir + d0 + lane * 4);
    sum += wv[0] * iv[0] + wv[1] * iv[1] + wv[2] * iv[2] + wv[3] * iv[3];
  }
#pragma unroll
  for (int off = 32; off; off >>= 1) sum += __shfl_xor(sum, off, 64);
  if (lane == 0) {
    float a = sum + bias[c];
    out[oidx] = a >= 0.f ? a : 0.01f * a;
  }
}

// ---------------- consolidated prep (tap-major wt):
// blocks [0,1024): fused MLP-layer-3 + padded/scaled/c8-blocked bf16 x
// blocks [1024,1600): conv_w (O,I,3,3) fp32 -> wt[tap][o][i] bf16.
__global__ void __launch_bounds__(256) prep_all(const float* __restrict__ t1,
                                                const float* __restrict__ w2,
                                                const float* __restrict__ b2,
                                                const float* __restrict__ x,
                                                const float* __restrict__ cw,
                                                unsigned short* __restrict__ xpad,
                                                unsigned short* __restrict__ wt) {
  int blk = blockIdx.x;
  int tid = threadIdx.x;

  if (blk >= 1024) {  // ---- prep_w part
    int idx = (blk - 1024) * 256 + tid;  // 9*256*64 = 147456 threads
    int t = idx / 16384;
    int r = idx - t * 16384;  // o*64 + i4
    int o = r >> 6, i4 = r & 63;
    ushort4v v;
#pragma unroll
    for (int j = 0; j < 4; j++) v[j] = f2bf(cw[(o * 256 + i4 * 4 + j) * 9 + t]);
    *(ushort4v*)(wt + ((size_t)(t * COUT + o)) * CIN + i4 * 4) = v;
    return;
  }

  // ---- prep_x part: blk = (b<<6) | (c8<<1) | h
  int h = blk & 1, c8 = (blk >> 1) & 31, b = blk >> 6;
  int wid = tid >> 6, lane = tid & 63;

  // MLP loads first (longest dependency chain: load -> shuffle tree -> 2 barriers)
  float tv = t1[b * CIN + tid];
  float pj[8];
#pragma unroll
  for (int j = 0; j < 8; j++) pj[j] = w2[(size_t)(c8 * 8 + j) * CIN + tid] * tv;

  // 16 independent x loads (2 pixel-groups x 8 channel-planes)
  const float* xb = x + ((size_t)(b * CIN + c8 * 8)) * (HH * WW);
  int gg0 = h * 512 + tid;  // pixel-group: hh=(gg>>4)+1, w0=(gg&15)*4+1
  int gg1 = gg0 + 256;
  int hh0 = (gg0 >> 4) + 1, w00 = (gg0 & 15) * 4 + 1;
  int hh1 = (gg1 >> 4) + 1, w01 = (gg1 & 15) * 4 + 1;
  int base0 = (hh0 - 1) * WW + (w00 - 1);
  int base1 = (hh1 - 1) * WW + (w01 - 1);
  f32x4 v0[8], v1[8];
#pragma unroll
  for (int j = 0; j < 8; j++) v0[j] = *(const f32x4*)(xb + j * (HH * WW) + base0);
#pragma unroll
  for (int j = 0; j < 8; j++) v1[j] = *(const f32x4*)(xb + j * (HH * WW) + base1);

  // butterfly-reduce the 8 style dots
#pragma unroll
  for (int off = 32; off; off >>= 1)
#pragma unroll
    for (int j = 0; j < 8; j++) pj[j] += __shfl_xor(pj[j], off, 64);
  __shared__ float red[4][8];
  __shared__ float sv_sh[8];
  if (lane == 0)
#pragma unroll
    for (int j = 0; j < 8; j++) red[wid][j] = pj[j];
  __syncthreads();
  if (tid < 8) {
    float a = red[0][tid] + red[1][tid] + red[2][tid] + red[3][tid] + b2[c8 * 8 + tid];
    sv_sh[tid] = a >= 0.f ? a : 0.01f * a;
  }
  __syncthreads();
  float sv[8];
#pragma unroll
  for (int j = 0; j < 8; j++) sv[j] = sv_sh[j];

  unsigned short* xp = xpad + ((size_t)(b * 32 + c8)) * PLANE;

  // zero border: half h covers 130 of the 260 border cells
  if (tid < 130) {
    int i = h * 130 + tid;
    int bh, bw;
    if (i < 66) { bh = 0; bw = i; }
    else if (i < 132) { bh = 65; bw = i - 66; }
    else if (i < 196) { bh = i - 132 + 1; bw = 0; }
    else { bh = i - 196 + 1; bw = 65; }
    ushort8 z = {0, 0, 0, 0, 0, 0, 0, 0};
    *(ushort8*)(xp + (bh * WP + bw) * 8) = z;
  }

  // convert + store (2 groups x 4 px x 8 ch = 2 x 64B contiguous per thread)
  unsigned short* op0 = xp + (hh0 * WP + w00) * 8;
  unsigned short* op1 = xp + (hh1 * WP + w01) * 8;
#pragma unroll
  for (int t2 = 0; t2 < 4; t2++) {
    ushort8 o;
#pragma unroll
    for (int j = 0; j < 8; j++) o[j] = f2bf(v0[j][t2] * sv[j]);
    *(ushort8*)(op0 + t2 * 8) = o;
  }
#pragma unroll
  for (int t2 = 0; t2 < 4; t2++) {
    ushort8 o;
#pragma unroll
    for (int j = 0; j < 8; j++) o[j] = f2bf(v1[j][t2] * sv[j]);
    *(ushort8*)(op1 + t2 * 8) = o;
  }
}

// ---------------- implicit-GEMM conv: BM=256 px, BN=256 out, BK=64
// Single-barrier double-buffered pipeline: both A and B staged via
// global_load_lds into 2x(32K+32K) LDS; stage of step s+1 is issued at the
// top of step s and has the full 64-MFMA/wave compute phase of cover before
// the barrier's vmcnt(0) drain. 8 waves (2x4), wave tile 128px x 64o.
__device__ __forceinline__ void gl2lds16(const void* g, void* l) {
  __builtin_amdgcn_global_load_lds((const __attribute__((address_space(1))) void*)g,
                                   (__attribute__((address_space(3))) void*)l, 16, 0, 0);
}

__global__ void __launch_bounds__(512, 1) gemm_conv(const unsigned short* __restrict__ xpad,
                                                    const unsigned short* __restrict__ wt,
                                                    float* __restrict__ out) {
  // LDS map (bytes): A buf0 [0,32K), A buf1 [32K,64K), B buf0 [64K,96K), B buf1 [96K,128K)
  __shared__ __align__(16) char lds[131072];
  int tid = threadIdx.x;
  int wid = tid >> 6, lane = tid & 63;
  int bid = blockIdx.x;
  // XCD swizzle: 256 blocks, 32 contiguous tiles (=2 images) per XCD.
  int m_t = (bid & 7) * 32 + (bid >> 3);
  int m0 = m_t << 8;                 // first pixel of tile (BM=256 = 4 image rows)
  int b = m0 >> 12;
  int h0 = (m0 >> 6) & 63;           // tile covers image rows h0..h0+3
  int wm = wid & 1, wn = wid >> 1;   // 2x4 wave grid, each wave 128x64

  f32x4 acc[8][4];
#pragma unroll
  for (int mi = 0; mi < 8; mi++)
#pragma unroll
    for (int ni = 0; ni < 4; ni++) acc[mi][ni] = (f32x4){0.f, 0.f, 0.f, 0.f};

  // ---- stager lane invariants (global lane id = tid)
  int p = tid >> 3;                  // pixel/o within a 64-row group
  int cs = tid & 7;                  // chunk slot in LDS row
  int gs = cs ^ (p & 7);             // XOR swizzle: LDS slot cs holds global chunk gs
  const unsigned short* aSt =
      xpad + ((size_t)((b * 32 + gs) * HP + h0)) * (WP * 8) + p * 8;  // step 0
  const unsigned short* bSt = wt + (size_t)p * CIN + gs * 8;          // step 0
  int dstOff = wid * 1024;

  // ---- reader frag offsets (bytes into lds), XOR-unswizzled
  int qa = lane >> 4;
  int rA = wm * 128 + (lane & 15);
  int rB = wn * 64 + (lane & 15);
  int offA0 = rA * 128 + ((qa ^ (lane & 7)) * 16);
  int offA1 = rA * 128 + (((qa + 4) ^ (lane & 7)) * 16);
  int offB0 = 65536 + rB * 128 + ((qa ^ (lane & 7)) * 16);
  int offB1 = 65536 + rB * 128 + (((qa + 4) ^ (lane & 7)) * 16);

#define STAGE(bo)                                       \
  do {                                                  \
    char* dA = lds + (bo) + dstOff;                     \
    char* dB = lds + 65536 + (bo) + dstOff;             \
    gl2lds16(aSt, dA);                                  \
    gl2lds16(aSt + WP * 8, dA + 8192);                  \
    gl2lds16(aSt + 2 * WP * 8, dA + 16384);             \
    gl2lds16(aSt + 3 * WP * 8, dA + 24576);             \
    gl2lds16(bSt, dB);                                  \
    gl2lds16(bSt + 64 * CIN, dB + 8192);                \
    gl2lds16(bSt + 128 * CIN, dB + 16384);              \
    gl2lds16(bSt + 192 * CIN, dB + 24576);              \
  } while (0)

  // prologue: stage step 0 into buffer 0, advance pointers to step 1
  STAGE(0);
  aSt += 8 * PLANE;  // kc2 0->1
  bSt += 64;
  __syncthreads();

  int bo = 0;
  for (int s = 0; s < 36; s++) {  // step s: tap = s>>2 (kh=t/3,kw=t%3), kc2 = s&3
    if (s < 35) {
      STAGE(bo ^ 32768);
      int sn = s + 1;  // step just staged; advance pointers to step sn+1
      if ((sn & 3) != 3) {
        aSt += 8 * PLANE;  // kc2++
        bSt += 64;
      } else {
        int tapn = sn >> 2;  // current tap; next transition is kw++/kh++
        aSt += (tapn % 3 != 2) ? (8 - 24 * PLANE) : ((WP - 2) * 8 - 24 * PLANE);
        bSt += COUT * CIN - 192;
      }
    }

    // compute step s from buffers at bo
    const char* Ab = lds + bo;
#pragma unroll
    for (int kb = 0; kb < 2; kb++) {
      int oa = kb ? offA1 : offA0;
      int ob = kb ? offB1 : offB0;
      bf16x8 av[8], bv[4];
#pragma unroll
      for (int mi = 0; mi < 8; mi++)
        av[mi] = *(const bf16x8*)(Ab + oa + mi * 2048);
#pragma unroll
      for (int ni = 0; ni < 4; ni++)
        bv[ni] = *(const bf16x8*)(Ab + ob + ni * 2048);
#pragma unroll
      for (int mi = 0; mi < 8; mi++)
#pragma unroll
        for (int ni = 0; ni < 4; ni++)
          acc[mi][ni] = __builtin_amdgcn_mfma_f32_16x16x32_bf16(av[mi], bv[ni],
                                                                acc[mi][ni], 0, 0, 0);
    }

    __syncthreads();
    bo ^= 32768;
  }
#undef STAGE

  // ---- epilogue: D row = pixel (quad*4+reg), col = o (lane&15)
  int pixbase = m0 & 4095;
  int quad = lane >> 4;
  int col = lane & 15;
#pragma unroll
  for (int mi = 0; mi < 8; mi++) {
    int pm = pixbase + wm * 128 + mi * 16 + quad * 4;
#pragma unroll
    for (int ni = 0; ni < 4; ni++) {
      int on = wn * 64 + ni * 16 + col;
      float* op = out + ((size_t)(b * COUT + on) << 12) + pm;
      *(f32x4*)op = acc[mi][ni];
    }
  }
}

extern "C" void kernel_launch(void* const* d_in, const int* in_sizes, int n_in,
                              void* d_out, int out_size, void* d_ws, size_t ws_size,
                              hipStream_t stream) {
  const float* x = (const float*)d_in[0];
  const float* y = (const float*)d_in[1];
  const float* w0 = (const float*)d_in[2];
  const float* b0 = (const float*)d_in[3];
  const float* w1 = (const float*)d_in[4];
  const float* b1 = (const float*)d_in[5];
  const float* w2 = (const float*)d_in[6];
  const float* b2 = (const float*)d_in[7];
  const float* cw = (const float*)d_in[8];
  float* out = (float*)d_out;

  char* ws = (char*)d_ws;
  float* t0 = (float*)ws;                              // 16 KiB
  float* t1 = (float*)(ws + 16384);                    // 16 KiB
  unsigned short* wt = (unsigned short*)(ws + 32768);  // 1.125 MiB
  unsigned short* xpad = (unsigned short*)(ws + 32768 + 9 * COUT * CIN * 2);

  mlp_layer<DCAT><<<BATCH * CIN / 4, 256, 0, stream>>>(y, w0, b0, t0);
  mlp_layer<CIN><<<BATCH * CIN / 4, 256, 0, stream>>>(t0, w1, b1, t1);
  prep_all<<<1024 + 576, 256, 0, stream>>>(t1, w2, b2, x, cw, xpad, wt);
  gemm_conv<<<BATCH * HH * WW / 256, 512, 0, stream>>>(xpad, wt, out);
}

// Round 4
// 202.952 us; speedup vs baseline: 1.0666x; 1.0313x over previous
//
#include <hip/hip_runtime.h>

typedef short bf16x8 __attribute__((ext_vector_type(8)));
typedef float f32x4 __attribute__((ext_vector_type(4)));
typedef unsigned short ushort8 __attribute__((ext_vector_type(8)));
typedef unsigned short ushort4v __attribute__((ext_vector_type(4)));

#define BATCH 16
#define DCAT 512
#define CIN 256
#define COUT 256
#define HH 64
#define WW 64
#define HP 66
#define WP 66
#define PLANE (HP * WP * 8)  // shorts per c8-plane

__device__ __forceinline__ unsigned short f2bf(float f) {
  unsigned int u = __float_as_uint(f);
  unsigned int r = (u + 0x7fffu + ((u >> 16) & 1u)) >> 16;
  return (unsigned short)r;
}

// ---------------- MLP layer: one wave per output element (b,c).
template <int IN_DIM>
__global__ void __launch_bounds__(256) mlp_layer(const float* __restrict__ in,
                                                 const float* __restrict__ w,
                                                 const float* __restrict__ bias,
                                                 float* __restrict__ out) {
  int wid = threadIdx.x >> 6, lane = threadIdx.x & 63;
  int oidx = blockIdx.x * 4 + wid;  // (b<<8)|c
  int b = oidx >> 8, c = oidx & 255;
  const float* wr = w + (size_t)c * IN_DIM;
  const float* ir = in + (size_t)b * IN_DIM;
  float sum = 0.f;
#pragma unroll
  for (int d0 = 0; d0 < IN_DIM; d0 += 256) {
    f32x4 wv = *(const f32x4*)(wr + d0 + lane * 4);
    f32x4 iv = *(const f32x4*)(ir + d0 + lane * 4);
    sum += wv[0] * iv[0] + wv[1] * iv[1] + wv[2] * iv[2] + wv[3] * iv[3];
  }
#pragma unroll
  for (int off = 32; off; off >>= 1) sum += __shfl_xor(sum, off, 64);
  if (lane == 0) {
    float a = sum + bias[c];
    out[oidx] = a >= 0.f ? a : 0.01f * a;
  }
}

// ---------------- consolidated prep (tap-major wt):
// blocks [0,1024): fused MLP-layer-3 + padded/scaled/c8-blocked bf16 x
// blocks [1024,1600): conv_w (O,I,3,3) fp32 -> wt[tap][o][i] bf16.
__global__ void __launch_bounds__(256) prep_all(const float* __restrict__ t1,
                                                const float* __restrict__ w2,
                                                const float* __restrict__ b2,
                                                const float* __restrict__ x,
                                                const float* __restrict__ cw,
                                                unsigned short* __restrict__ xpad,
                                                unsigned short* __restrict__ wt) {
  int blk = blockIdx.x;
  int tid = threadIdx.x;

  if (blk >= 1024) {  // ---- prep_w part
    int idx = (blk - 1024) * 256 + tid;  // 9*256*64 = 147456 threads
    int t = idx / 16384;
    int r = idx - t * 16384;  // o*64 + i4
    int o = r >> 6, i4 = r & 63;
    ushort4v v;
#pragma unroll
    for (int j = 0; j < 4; j++) v[j] = f2bf(cw[(o * 256 + i4 * 4 + j) * 9 + t]);
    *(ushort4v*)(wt + ((size_t)(t * COUT + o)) * CIN + i4 * 4) = v;
    return;
  }

  // ---- prep_x part: blk = (b<<6) | (c8<<1) | h
  int h = blk & 1, c8 = (blk >> 1) & 31, b = blk >> 6;
  int wid = tid >> 6, lane = tid & 63;

  // MLP loads first (longest dependency chain: load -> shuffle tree -> 2 barriers)
  float tv = t1[b * CIN + tid];
  float pj[8];
#pragma unroll
  for (int j = 0; j < 8; j++) pj[j] = w2[(size_t)(c8 * 8 + j) * CIN + tid] * tv;

  // 16 independent x loads (2 pixel-groups x 8 channel-planes)
  const float* xb = x + ((size_t)(b * CIN + c8 * 8)) * (HH * WW);
  int gg0 = h * 512 + tid;  // pixel-group: hh=(gg>>4)+1, w0=(gg&15)*4+1
  int gg1 = gg0 + 256;
  int hh0 = (gg0 >> 4) + 1, w00 = (gg0 & 15) * 4 + 1;
  int hh1 = (gg1 >> 4) + 1, w01 = (gg1 & 15) * 4 + 1;
  int base0 = (hh0 - 1) * WW + (w00 - 1);
  int base1 = (hh1 - 1) * WW + (w01 - 1);
  f32x4 v0[8], v1[8];
#pragma unroll
  for (int j = 0; j < 8; j++) v0[j] = *(const f32x4*)(xb + j * (HH * WW) + base0);
#pragma unroll
  for (int j = 0; j < 8; j++) v1[j] = *(const f32x4*)(xb + j * (HH * WW) + base1);

  // butterfly-reduce the 8 style dots
#pragma unroll
  for (int off = 32; off; off >>= 1)
#pragma unroll
    for (int j = 0; j < 8; j++) pj[j] += __shfl_xor(pj[j], off, 64);
  __shared__ float red[4][8];
  __shared__ float sv_sh[8];
  if (lane == 0)
#pragma unroll
    for (int j = 0; j < 8; j++) red[wid][j] = pj[j];
  __syncthreads();
  if (tid < 8) {
    float a = red[0][tid] + red[1][tid] + red[2][tid] + red[3][tid] + b2[c8 * 8 + tid];
    sv_sh[tid] = a >= 0.f ? a : 0.01f * a;
  }
  __syncthreads();
  float sv[8];
#pragma unroll
  for (int j = 0; j < 8; j++) sv[j] = sv_sh[j];

  unsigned short* xp = xpad + ((size_t)(b * 32 + c8)) * PLANE;

  // zero border: half h covers 130 of the 260 border cells
  if (tid < 130) {
    int i = h * 130 + tid;
    int bh, bw;
    if (i < 66) { bh = 0; bw = i; }
    else if (i < 132) { bh = 65; bw = i - 66; }
    else if (i < 196) { bh = i - 132 + 1; bw = 0; }
    else { bh = i - 196 + 1; bw = 65; }
    ushort8 z = {0, 0, 0, 0, 0, 0, 0, 0};
    *(ushort8*)(xp + (bh * WP + bw) * 8) = z;
  }

  // convert + store (2 groups x 4 px x 8 ch = 2 x 64B contiguous per thread)
  unsigned short* op0 = xp + (hh0 * WP + w00) * 8;
  unsigned short* op1 = xp + (hh1 * WP + w01) * 8;
#pragma unroll
  for (int t2 = 0; t2 < 4; t2++) {
    ushort8 o;
#pragma unroll
    for (int j = 0; j < 8; j++) o[j] = f2bf(v0[j][t2] * sv[j]);
    *(ushort8*)(op0 + t2 * 8) = o;
  }
#pragma unroll
  for (int t2 = 0; t2 < 4; t2++) {
    ushort8 o;
#pragma unroll
    for (int j = 0; j < 8; j++) o[j] = f2bf(v1[j][t2] * sv[j]);
    *(ushort8*)(op1 + t2 * 8) = o;
  }
}

// ---------------- implicit-GEMM conv: BM=256 px, BN=256 out, BK=64
// 4-phase counted-vmcnt pipeline (T3+T4+T5). Per K-step, 4 phases of
// {ds_reads, 2 stage-issues, [vmcnt(2)], s_barrier, lgkmcnt(0), 16 MFMA}.
// Stage FIFO per step: B0,B1 | B2,B3 | A0,A2 | A1,A3. vmcnt(2) at phase-0
// barrier (waits prev A1,A3) and phase-3 barrier (waits B0-B3,A0,A2);
// vmcnt never drains to 0 in the main loop.
__device__ __forceinline__ void gl2lds16(const void* g, void* l) {
  __builtin_amdgcn_global_load_lds((const __attribute__((address_space(1))) void*)g,
                                   (__attribute__((address_space(3))) void*)l, 16, 0, 0);
}

#define RD_AV(DST, OFF)                                   \
  _Pragma("unroll")                                       \
  for (int mi = 0; mi < 4; mi++)                          \
    DST[mi] = *(const bf16x8*)(Ab + (OFF) + mi * 2048);

#define RD_BV(DST, OFF)                                   \
  _Pragma("unroll")                                       \
  for (int ni = 0; ni < 4; ni++)                          \
    DST[ni] = *(const bf16x8*)(Bb + (OFF) + ni * 2048);

#define CLUSTER(MB, AV, BV)                                                 \
  do {                                                                      \
    __builtin_amdgcn_s_setprio(1);                                          \
    _Pragma("unroll")                                                       \
    for (int mi = 0; mi < 4; mi++)                                          \
      _Pragma("unroll")                                                     \
      for (int ni = 0; ni < 4; ni++)                                        \
        acc[(MB) + mi][ni] = __builtin_amdgcn_mfma_f32_16x16x32_bf16(       \
            AV[mi], BV[ni], acc[(MB) + mi][ni], 0, 0, 0);                   \
    __builtin_amdgcn_s_setprio(0);                                          \
  } while (0)

#define WAIT_LGKM0()                                        \
  asm volatile("s_waitcnt lgkmcnt(0)" ::: "memory");        \
  __builtin_amdgcn_sched_barrier(0)

__global__ void __launch_bounds__(512, 1) gemm_conv(const unsigned short* __restrict__ xpad,
                                                    const unsigned short* __restrict__ wt,
                                                    float* __restrict__ out) {
  // LDS map (bytes): A buf0 [0,32K), A buf1 [32K,64K), B buf0 [64K,96K), B buf1 [96K,128K)
  __shared__ __align__(16) char lds[131072];
  int tid = threadIdx.x;
  int wid = tid >> 6, lane = tid & 63;
  int bid = blockIdx.x;
  // XCD swizzle: 256 blocks, 32 contiguous tiles (=2 images) per XCD.
  int m_t = (bid & 7) * 32 + (bid >> 3);
  int m0 = m_t << 8;                 // first pixel of tile (BM=256 = 4 image rows)
  int b = m0 >> 12;
  int h0 = (m0 >> 6) & 63;           // tile covers image rows h0..h0+3
  int wm = wid & 1, wn = wid >> 1;   // 2x4 wave grid, each wave 128x64

  f32x4 acc[8][4];
#pragma unroll
  for (int mi = 0; mi < 8; mi++)
#pragma unroll
    for (int ni = 0; ni < 4; ni++) acc[mi][ni] = (f32x4){0.f, 0.f, 0.f, 0.f};

  // ---- stager lane invariants (global lane id = tid)
  int p = tid >> 3;                  // pixel/o within a 64-row group
  int cs = tid & 7;                  // chunk slot in LDS row
  int gs = cs ^ (p & 7);             // XOR swizzle: LDS slot cs holds global chunk gs
  const unsigned short* aSt =
      xpad + ((size_t)((b * 32 + gs) * HP + h0)) * (WP * 8) + p * 8;  // step 0
  const unsigned short* bSt = wt + (size_t)p * CIN + gs * 8;          // step 0
  int dstOff = wid * 1024;

  // ---- reader frag offsets (bytes, relative to A / B region base), XOR-unswizzled
  int qa = lane >> 4;
  int rA = wm * 128 + (lane & 15);
  int rB = wn * 64 + (lane & 15);
  int offA0 = rA * 128 + ((qa ^ (lane & 7)) * 16);
  int offA1 = rA * 128 + (((qa + 4) ^ (lane & 7)) * 16);
  int offB0 = rB * 128 + ((qa ^ (lane & 7)) * 16);
  int offB1 = rB * 128 + (((qa + 4) ^ (lane & 7)) * 16);

  // prologue: stage step 0 into buffer 0, advance pointers to step 1
  {
    char* dA = lds + dstOff;
    char* dB = lds + 65536 + dstOff;
    gl2lds16(aSt, dA);
    gl2lds16(aSt + WP * 8, dA + 8192);
    gl2lds16(aSt + 2 * WP * 8, dA + 16384);
    gl2lds16(aSt + 3 * WP * 8, dA + 24576);
    gl2lds16(bSt, dB);
    gl2lds16(bSt + 64 * CIN, dB + 8192);
    gl2lds16(bSt + 128 * CIN, dB + 16384);
    gl2lds16(bSt + 192 * CIN, dB + 24576);
  }
  aSt += 8 * PLANE;  // kc2 0->1
  bSt += 64;
  asm volatile("s_waitcnt vmcnt(0)" ::: "memory");
  __builtin_amdgcn_s_barrier();

  int bo = 0;
  for (int s = 0; s < 35; s++) {  // step s: tap = s>>2 (kh=t/3,kw=t%3), kc2 = s&3
    const char* Ab = lds + bo;
    const char* Bb = lds + 65536 + bo;
    char* dA = lds + (bo ^ 32768) + dstOff;
    char* dB = lds + 65536 + (bo ^ 32768) + dstOff;
    bf16x8 av[4], bv[4], aw[4], av2[4], bw[4], aw2[4];

    // ---- phase 0: av mihalf0 kb0 + bv kb0; stage B0,B1
    RD_AV(av, offA0);
    RD_BV(bv, offB0);
    gl2lds16(bSt, dB);
    gl2lds16(bSt + 64 * CIN, dB + 8192);
    asm volatile("s_waitcnt vmcnt(2)" ::: "memory");  // prev step's A1,A3 landed
    __builtin_amdgcn_s_barrier();
    WAIT_LGKM0();
    CLUSTER(0, av, bv);

    // ---- phase 1: av mihalf1 kb0; stage B2,B3
    RD_AV(aw, offA0 + 8192);
    gl2lds16(bSt + 128 * CIN, dB + 16384);
    gl2lds16(bSt + 192 * CIN, dB + 24576);
    __builtin_amdgcn_s_barrier();
    WAIT_LGKM0();
    CLUSTER(4, aw, bv);

    // ---- phase 2: av mihalf0 kb1 + bv kb1; stage A0,A2
    RD_AV(av2, offA1);
    RD_BV(bw, offB1);
    gl2lds16(aSt, dA);
    gl2lds16(aSt + 2 * WP * 8, dA + 16384);
    __builtin_amdgcn_s_barrier();
    WAIT_LGKM0();
    CLUSTER(0, av2, bw);

    // ---- phase 3: av mihalf1 kb1; stage A1,A3
    RD_AV(aw2, offA1 + 8192);
    gl2lds16(aSt + WP * 8, dA + 8192);
    gl2lds16(aSt + 3 * WP * 8, dA + 24576);
    asm volatile("s_waitcnt vmcnt(2)" ::: "memory");  // B0-B3,A0,A2 landed; A1,A3 fly
    __builtin_amdgcn_s_barrier();
    WAIT_LGKM0();
    CLUSTER(4, aw2, bw);

    // ---- advance stage pointers: staged step s+1, move to step s+2
    int sn = s + 1;
    if ((sn & 3) != 3) {
      aSt += 8 * PLANE;  // kc2++
      bSt += 64;
    } else {
      int tapn = sn >> 2;  // tap of step s+1; transition is kw++/kh++
      aSt += (tapn % 3 != 2) ? (8 - 24 * PLANE) : ((WP - 2) * 8 - 24 * PLANE);
      bSt += COUT * CIN - 192;
    }
    bo ^= 32768;
  }

  // ---- tail step 35: no staging, no barriers needed after the drain
  {
    const char* Ab = lds + bo;
    const char* Bb = lds + 65536 + bo;
    asm volatile("s_waitcnt vmcnt(0)" ::: "memory");  // last A1,A3 landed
    __builtin_amdgcn_s_barrier();                     // cross-wave visibility
    bf16x8 av[4], bv[4];
    RD_AV(av, offA0);
    RD_BV(bv, offB0);
    CLUSTER(0, av, bv);
    RD_AV(av, offA0 + 8192);
    CLUSTER(4, av, bv);
    RD_AV(av, offA1);
    RD_BV(bv, offB1);
    CLUSTER(0, av, bv);
    RD_AV(av, offA1 + 8192);
    CLUSTER(4, av, bv);
  }

  // ---- epilogue: D row = pixel (quad*4+reg), col = o (lane&15)
  int pixbase = m0 & 4095;
  int quad = lane >> 4;
  int col = lane & 15;
#pragma unroll
  for (int mi = 0; mi < 8; mi++) {
    int pm = pixbase + wm * 128 + mi * 16 + quad * 4;
#pragma unroll
    for (int ni = 0; ni < 4; ni++) {
      int on = wn * 64 + ni * 16 + col;
      float* op = out + ((size_t)(b * COUT + on) << 12) + pm;
      *(f32x4*)op = acc[mi][ni];
    }
  }
}

extern "C" void kernel_launch(void* const* d_in, const int* in_sizes, int n_in,
                              void* d_out, int out_size, void* d_ws, size_t ws_size,
                              hipStream_t stream) {
  const float* x = (const float*)d_in[0];
  const float* y = (const float*)d_in[1];
  const float* w0 = (const float*)d_in[2];
  const float* b0 = (const float*)d_in[3];
  const float* w1 = (const float*)d_in[4];
  const float* b1 = (const float*)d_in[5];
  const float* w2 = (const float*)d_in[6];
  const float* b2 = (const float*)d_in[7];
  const float* cw = (const float*)d_in[8];
  float* out = (float*)d_out;

  char* ws = (char*)d_ws;
  float* t0 = (float*)ws;                              // 16 KiB
  float* t1 = (float*)(ws + 16384);                    // 16 KiB
  unsigned short* wt = (unsigned short*)(ws + 32768);  // 1.125 MiB
  unsigned short* xpad = (unsigned short*)(ws + 32768 + 9 * COUT * CIN * 2);

  mlp_layer<DCAT><<<BATCH * CIN / 4, 256, 0, stream>>>(y, w0, b0, t0);
  mlp_layer<CIN><<<BATCH * CIN / 4, 256, 0, stream>>>(t0, w1, b1, t1);
  prep_all<<<1024 + 576, 256, 0, stream>>>(t1, w2, b2, x, cw, xpad, wt);
  gemm_conv<<<BATCH * HH * WW / 256, 512, 0, stream>>>(xpad, wt, out);
}